// Round 7
// baseline (208.140 us; speedup 1.0000x reference)
//
#include <hip/hip_runtime.h>
#include <math.h>

typedef short v4s __attribute__((ext_vector_type(4)));
typedef short v8s __attribute__((ext_vector_type(8)));
typedef float v4f __attribute__((ext_vector_type(4)));

#define L2E 1.4426950408889634f
#define INV_SCALE 0.08838834764831845f       // 1/sqrt(128)
#define SCL2 (INV_SCALE * L2E)               // folded scale for exp2

static __device__ __forceinline__ short f2bf(float x) {
    union { float f; unsigned u; } c; c.f = x;
    unsigned u = c.u;
    unsigned r = (u + 0x7fffu + ((u >> 16) & 1u)) >> 16;  // RNE
    return (short)r;
}

static __device__ __forceinline__ v4f mfma16(v4s a, v4s b, v4f c) {
#if __has_builtin(__builtin_amdgcn_mfma_f32_16x16x16_bf16)
    return __builtin_amdgcn_mfma_f32_16x16x16_bf16(a, b, c, 0, 0, 0);
#else
    return __builtin_amdgcn_mfma_f32_16x16x16bf16_1k(a, b, c, 0, 0, 0);
#endif
}

typedef __attribute__((address_space(3))) void lds_vt;
typedef __attribute__((address_space(1))) const void gl_vt;
static __device__ __forceinline__ void gload_lds16(const void* g, void* l) {
    __builtin_amdgcn_global_load_lds((gl_vt*)g, (lds_vt*)l, 16, 0, 0);
}

// ---- P0 fused: 512 blocks. isel=0: ctx gemm->Qa. isel=1: qry gemm->Ka
// PLUS fused qry transpose->VaT (plain [d][kv] bf16) + maskadd.
// qry is read ONCE (the gemm's X loads feed the transpose via LDS Tt).
__global__ __launch_bounds__(256) void k_pre(const float* __restrict__ ctx,
                                             const float* __restrict__ qry,
                                             const float* __restrict__ Win,
                                             const float* __restrict__ Wmem,
                                             const int* __restrict__ qmask,
                                             short* __restrict__ Qa,
                                             short* __restrict__ Ka,
                                             short* __restrict__ VaT,
                                             float* __restrict__ maskadd) {
    __shared__ __align__(16) short WtS[128 * 132];      // 33792 B
    __shared__ __align__(16) short Tt[256 * 72];        // 36864 B ([k][row64+pad])
    int x = blockIdx.x;
    int tid = threadIdx.x;
    int msel = x & 255, isel = x >> 8;
    const float* X = isel ? qry : ctx;
    const float* W = isel ? Wmem : Win;
    short* Y = isel ? Ka : Qa;

    int w = tid >> 6, lane = tid & 63;
    int ln = lane & 15, qd = lane >> 4;
    int m0 = msel * 64 + w * 16;
    v4f zero = {0.f, 0.f, 0.f, 0.f};
    v4f o[8];
#pragma unroll
    for (int i = 0; i < 8; ++i) o[i] = zero;

#pragma unroll 1
    for (int kh = 0; kh < 2; ++kh) {
        if (kh) __syncthreads();                        // protect WtS reuse
        // stage W k-half: 128 f x 128 k
#pragma unroll 8
        for (int i = 0; i < 64; ++i) {
            int id = i * 256 + tid;
            int k = id >> 7, fp = id & 127;
            WtS[fp * 132 + k] = f2bf(W[(kh * 128 + k) * 128 + fp]);
        }
        __syncthreads();
#pragma unroll
        for (int kk = 0; kk < 4; ++kk) {
            const float* xp = X + (size_t)(m0 + ln) * 256 + kh * 128 + kk * 32 + qd * 8;
            float4 x0 = *(const float4*)xp;
            float4 x1 = *(const float4*)(xp + 4);
            v8s a;
            a[0] = f2bf(x0.x); a[1] = f2bf(x0.y); a[2] = f2bf(x0.z); a[3] = f2bf(x0.w);
            a[4] = f2bf(x1.x); a[5] = f2bf(x1.y); a[6] = f2bf(x1.z); a[7] = f2bf(x1.w);
            if (isel) {                                  // fused transpose staging
#pragma unroll
                for (int si = 0; si < 8; ++si)
                    Tt[(kh * 128 + kk * 32 + qd * 8 + si) * 72 + (w * 16 + ln)] = a[si];
            }
#pragma unroll
            for (int nt = 0; nt < 8; ++nt) {
                v8s bfr = *(const v8s*)(WtS + (nt * 16 + ln) * 132 + kk * 32 + qd * 8);
                o[nt] = __builtin_amdgcn_mfma_f32_16x16x32_bf16(a, bfr, o[nt], 0, 0, 0);
            }
        }
    }
#pragma unroll
    for (int nt = 0; nt < 8; ++nt) {
#pragma unroll
        for (int r = 0; r < 4; ++r) {
            float v = o[nt][r];
            v = v > 0.f ? v : 0.01f * (__expf(v) - 1.f);
            Y[(size_t)(m0 + qd * 4 + r) * 128 + nt * 16 + ln] = f2bf(v);
        }
    }

    if (isel) {
        __syncthreads();                                 // Tt complete
        int b2 = msel >> 5, q0 = (msel & 31) * 64;
        int dr = tid >> 3, j = tid & 7;
#pragma unroll
        for (int i = 0; i < 8; ++i) {
            int d = dr + i * 32;
            v8s vv = *(const v8s*)(Tt + d * 72 + j * 8);
            *(v8s*)(VaT + ((size_t)(b2 * 256 + d)) * 2048 + q0 + j * 8) = vv;
        }
        if (tid < 64) {
            int qq = b2 * 2048 + q0 + tid;
            maskadd[qq] = (qmask[qq] > 0) ? 0.f : -__builtin_inff();
        }
    }
}

// ------------- flash attention: register-P, tile-granular prefetch --------
// 256 blocks x 512 thr. Wave w: g=w>>2 (kv half), cw=(w>>1)&1 (32 c),
// dv=w&1 (128 d). Register-P: QK via mfma(K,Q) leaves S' in exactly the
// A-fragment layout of v_mfma_f32_16x16x16_bf16 -> softmax+PV lane-local,
// no P through LDS. Per 64-kv tile:
//   top: vmcnt(0)+lgkmcnt(0)+barrier (everything in flight is >=400cyc old
//        -> cheap, and SAFE: no hand-counted waits), then issue stage(t+1)
//        (full-tile window ~1500cyc).
//   kf(t+1)+mask(t+1) (20 loads) issued AFTER QK s=3's last kf(t) read
//   (WAR-pinned); they precede stage(t+1) in issue order, so the compiler's
//   own wait before QK(t+1) is a counted vmcnt(8) that leaves the stage
//   DMAs flying. (R6 bug: stage issued BEFORE per-substep kf loads ->
//   in-order vmcnt forced a full stage drain per sub-step.)
__global__ __launch_bounds__(512, 2) void k_attn(const short* __restrict__ Qa,
                                                 const short* __restrict__ Ka,
                                                 const short* __restrict__ VaT,
                                                 const float* __restrict__ maskadd,
                                                 float* __restrict__ out) {
    __shared__ __align__(16) short VaS[2][2][256 * 64];  // 128 KB [grp][buf][d][kv]
    __shared__ float lS[256];                            // [8 waves][32 c]

    int blk = blockIdx.x;
    int b = blk & 7;
    int c0 = (blk >> 3) * 64;

    int tid = threadIdx.x;
    int w = tid >> 6, lane = tid & 63, ln = lane & 15, qd = lane >> 4;
    int g = w >> 2, wl = w & 3, cw = (w >> 1) & 1, dv = w & 1;
    int kv0 = g * 1024;

    const short* kbase = Ka + ((size_t)(b * 2048 + kv0 + ln)) * 128 + qd * 8;
    const short* vbase = VaT + (size_t)b * 256 * 2048;
    const float* mbase = maskadd + b * 2048 + kv0 + qd * 4;

    // Q fragments: 2 c-tiles of 16 (B-operand layout), resident
    v8s qf[2][4];
#pragma unroll
    for (int ct = 0; ct < 2; ++ct) {
        const short* qp = Qa + ((size_t)(b * 2048 + c0 + cw * 32 + ct * 16 + ln)) * 128 + qd * 8;
#pragma unroll
        for (int kk = 0; kk < 4; ++kk) qf[ct][kk] = *(const v8s*)(qp + kk * 32);
    }

    v4f zero = {0.f, 0.f, 0.f, 0.f};
    v4f o[2][8];                            // [ct][dt] -> out[c][dv*128+dt*16+ln]
#pragma unroll
    for (int i = 0; i < 2; ++i)
#pragma unroll
        for (int j = 0; j < 8; ++j) o[i][j] = zero;
    float lacc[2] = {0.f, 0.f};

    // group-cooperative stage of V tile [256 d][64 kv] for window q0s.
    // LDS granule (16B) u of row d holds global granule u^(d&7)
    // (pre-swizzled source, linear dest) -> near-conflict-free PV b64 reads.
    auto stageV = [&](int q0s, int buf) {
        short* ldsb = &VaS[g][buf][0];
#pragma unroll
        for (int j = 0; j < 8; ++j) {
            int U = j * 256 + wl * 64 + lane;
            int d = U >> 3, u = U & 7;
            gload_lds16(vbase + (size_t)d * 2048 + q0s + ((u ^ (d & 7)) << 3),
                        ldsb + (size_t)(j * 256 + wl * 64) * 8);
        }
    };

    // K tile fragments + mask, tile-granular register buffer
    v8s kfr[4][4];
    float4 mkr[4];

    // ---- prologue: stage V(0); load kf(0)+mask(0) ----
    stageV(kv0, 0);
    {
        const short* kt = kbase;
#pragma unroll
        for (int s = 0; s < 4; ++s) {
#pragma unroll
            for (int kk = 0; kk < 4; ++kk)
                kfr[s][kk] = *(const v8s*)(kt + s * 2048 + kk * 32);
            mkr[s] = *(const float4*)(mbase + s * 16);
        }
    }

#pragma unroll 1
    for (int t = 0; t < 16; ++t) {
        // everything outstanding (stage(t), kf(t)) is >= one phase old
        asm volatile("s_waitcnt vmcnt(0) lgkmcnt(0)" ::: "memory");
        __builtin_amdgcn_s_barrier();        // V buffer swap safe
        stageV(kv0 + ((t + 1) & 15) * 64, (t + 1) & 1);   // full-tile window

        const short* vs = &VaS[g][t & 1][0];
#pragma unroll
        for (int s = 0; s < 4; ++s) {
            v4s pw[2];
#pragma unroll
            for (int ct = 0; ct < 2; ++ct) {
                v4f sa = zero;
#pragma unroll
                for (int kk = 0; kk < 4; ++kk)
                    sa = __builtin_amdgcn_mfma_f32_16x16x32_bf16(kfr[s][kk], qf[ct][kk], sa, 0, 0, 0);
                int cg = c0 + cw * 32 + ct * 16 + ln;
                int kvg = kv0 + t * 64 + s * 16 + qd * 4;
#pragma unroll
                for (int r = 0; r < 4; ++r) {
                    float v = sa[r] * SCL2 + (&mkr[s].x)[r];
                    if (kvg + r == cg) v = -__builtin_inff();
                    float p = exp2f(v);
                    lacc[ct] += p;
                    pw[ct][r] = f2bf(p);
                }
            }
            if (s == 3) {
                // last kf(t) read done (WAR pins these after the QK above);
                // issued BEFORE stage(t+1)? No: stage went first this tile,
                // but these precede NEXT tile's stage -> compiler's wait
                // before QK(t+1) is counted vmcnt(8). Window ~PV s=3.
                const short* kt = kbase + (size_t)(((t + 1) & 15)) * 8192;
#pragma unroll
                for (int s2 = 0; s2 < 4; ++s2) {
#pragma unroll
                    for (int kk = 0; kk < 4; ++kk)
                        kfr[s2][kk] = *(const v8s*)(kt + s2 * 2048 + kk * 32);
                    mkr[s2] = *(const float4*)(mbase + ((t + 1) & 15) * 64 + s2 * 16);
                }
            }
            // PV: pw is already the 16x16x16 A-fragment; V b64 from LDS
#pragma unroll
            for (int dt = 0; dt < 8; ++dt) {
                int d = dv * 128 + dt * 16 + ln;
                v4s vf = *(const v4s*)(vs + d * 64 +
                          (((s * 2 + (qd >> 1)) ^ (d & 7)) << 3) + ((qd & 1) << 2));
                o[0][dt] = mfma16(pw[0], vf, o[0][dt]);
                o[1][dt] = mfma16(pw[1], vf, o[1][dt]);
            }
        }
    }

    // ---- epilogue: drain, l reduce, cross-group O merge via LDS ----
    asm volatile("s_waitcnt vmcnt(0)" ::: "memory");
    __syncthreads();

    float lv0 = lacc[0], lv1 = lacc[1];
    lv0 += __shfl_xor(lv0, 16); lv0 += __shfl_xor(lv0, 32);
    lv1 += __shfl_xor(lv1, 16); lv1 += __shfl_xor(lv1, 32);
    if (lane < 16) { lS[w * 32 + ln] = lv0; lS[w * 32 + 16 + ln] = lv1; }
    __syncthreads();

    float* OS = (float*)&VaS[0][0][0];       // [64 c][260 d-pad] f32, 66.6 KB
    if (g == 1) {
#pragma unroll
        for (int ct = 0; ct < 2; ++ct) {
            int cl = cw * 32 + ct * 16 + qd * 4;
#pragma unroll
            for (int r = 0; r < 4; ++r)
#pragma unroll
                for (int dt = 0; dt < 8; ++dt)
                    OS[(cl + r) * 260 + dv * 128 + dt * 16 + ln] = o[ct][dt][r];
        }
    }
    __syncthreads();
    if (g == 0) {
#pragma unroll
        for (int ct = 0; ct < 2; ++ct) {
            int cl = cw * 32 + ct * 16 + qd * 4;
#pragma unroll
            for (int r = 0; r < 4; ++r) {
                float ltot = lS[w * 32 + ct * 16 + qd * 4 + r]
                           + lS[(w + 4) * 32 + ct * 16 + qd * 4 + r];
                float inv = 1.f / ltot;
                size_t rowg = (size_t)(b * 2048 + c0 + cl + r);
#pragma unroll
                for (int dt = 0; dt < 8; ++dt) {
                    int col = dv * 128 + dt * 16 + ln;
                    out[rowg * 256 + col] = (o[ct][dt][r] + OS[(cl + r) * 260 + col]) * inv;
                }
            }
        }
    }
}

extern "C" void kernel_launch(void* const* d_in, const int* in_sizes, int n_in,
                              void* d_out, int out_size, void* d_ws, size_t ws_size,
                              hipStream_t stream) {
    const float* ctx  = (const float*)d_in[0];
    const float* qry  = (const float*)d_in[1];
    const float* win  = (const float*)d_in[2];
    const float* wmem = (const float*)d_in[3];
    const int* qmask  = (const int*)d_in[4];
    float* out = (float*)d_out;

    char* ws = (char*)d_ws;
    short* Qa      = (short*)(ws);                          // 4 MB
    short* Ka      = (short*)(ws + (4u << 20));             // 4 MB
    short* VaT     = (short*)(ws + (8u << 20));             // 8 MB (plain [d][kv])
    float* maskadd = (float*)(ws + (16u << 20));            // 64 KB

    k_pre<<<dim3(512), 256, 0, stream>>>(ctx, qry, win, wmem, qmask,
                                         Qa, Ka, VaT, maskadd);
    k_attn<<<dim3(256), 512, 0, stream>>>(Qa, Ka, VaT, maskadd, out);
}

// Round 8
// 144.758 us; speedup vs baseline: 1.4378x; 1.4378x over previous
//
#include <hip/hip_runtime.h>
#include <math.h>

typedef short v4s __attribute__((ext_vector_type(4)));
typedef short v8s __attribute__((ext_vector_type(8)));
typedef float v4f __attribute__((ext_vector_type(4)));

#define L2E 1.4426950408889634f
#define INV_SCALE 0.08838834764831845f       // 1/sqrt(128)
#define SCL2 (INV_SCALE * L2E)               // folded scale for exp2

static __device__ __forceinline__ short f2bf(float x) {
    union { float f; unsigned u; } c; c.f = x;
    unsigned u = c.u;
    unsigned r = (u + 0x7fffu + ((u >> 16) & 1u)) >> 16;  // RNE
    return (short)r;
}

typedef __attribute__((address_space(3))) void lds_vt;
typedef __attribute__((address_space(1))) const void gl_vt;
static __device__ __forceinline__ void gload_lds16(const void* g, void* l) {
    __builtin_amdgcn_global_load_lds((gl_vt*)g, (lds_vt*)l, 16, 0, 0);
}

// ---- P0 fused: 512 blocks. isel=0: ctx gemm->Qa. isel=1: qry gemm->Ka
// PLUS fused qry transpose->VaT + maskadd. qry is read ONCE (the gemm's X
// loads feed the transpose via LDS Tt). VaT is written with the chunk-XOR
// swizzle (original 16B granule j of row d stored at position j^(d&7)) --
// the involution k_attn's stage/PV reads assume (R0/R3 format).
__global__ __launch_bounds__(256) void k_pre(const float* __restrict__ ctx,
                                             const float* __restrict__ qry,
                                             const float* __restrict__ Win,
                                             const float* __restrict__ Wmem,
                                             const int* __restrict__ qmask,
                                             short* __restrict__ Qa,
                                             short* __restrict__ Ka,
                                             short* __restrict__ VaT,
                                             float* __restrict__ maskadd) {
    __shared__ __align__(16) short WtS[128 * 132];      // 33792 B
    __shared__ __align__(16) short Tt[256 * 72];        // 36864 B ([k][row64+pad])
    int x = blockIdx.x;
    int tid = threadIdx.x;
    int msel = x & 255, isel = x >> 8;
    const float* X = isel ? qry : ctx;
    const float* W = isel ? Wmem : Win;
    short* Y = isel ? Ka : Qa;

    int w = tid >> 6, lane = tid & 63;
    int ln = lane & 15, qd = lane >> 4;
    int m0 = msel * 64 + w * 16;
    v4f zero = {0.f, 0.f, 0.f, 0.f};
    v4f o[8];
#pragma unroll
    for (int i = 0; i < 8; ++i) o[i] = zero;

#pragma unroll 1
    for (int kh = 0; kh < 2; ++kh) {
        if (kh) __syncthreads();                        // protect WtS reuse
        // stage W k-half: 128 f x 128 k
#pragma unroll 8
        for (int i = 0; i < 64; ++i) {
            int id = i * 256 + tid;
            int k = id >> 7, fp = id & 127;
            WtS[fp * 132 + k] = f2bf(W[(kh * 128 + k) * 128 + fp]);
        }
        __syncthreads();
#pragma unroll
        for (int kk = 0; kk < 4; ++kk) {
            const float* xp = X + (size_t)(m0 + ln) * 256 + kh * 128 + kk * 32 + qd * 8;
            float4 x0 = *(const float4*)xp;
            float4 x1 = *(const float4*)(xp + 4);
            v8s a;
            a[0] = f2bf(x0.x); a[1] = f2bf(x0.y); a[2] = f2bf(x0.z); a[3] = f2bf(x0.w);
            a[4] = f2bf(x1.x); a[5] = f2bf(x1.y); a[6] = f2bf(x1.z); a[7] = f2bf(x1.w);
            if (isel) {                                  // fused transpose staging
#pragma unroll
                for (int si = 0; si < 8; ++si)
                    Tt[(kh * 128 + kk * 32 + qd * 8 + si) * 72 + (w * 16 + ln)] = a[si];
            }
#pragma unroll
            for (int nt = 0; nt < 8; ++nt) {
                v8s bfr = *(const v8s*)(WtS + (nt * 16 + ln) * 132 + kk * 32 + qd * 8);
                o[nt] = __builtin_amdgcn_mfma_f32_16x16x32_bf16(a, bfr, o[nt], 0, 0, 0);
            }
        }
    }
#pragma unroll
    for (int nt = 0; nt < 8; ++nt) {
#pragma unroll
        for (int r = 0; r < 4; ++r) {
            float v = o[nt][r];
            v = v > 0.f ? v : 0.01f * (__expf(v) - 1.f);
            Y[(size_t)(m0 + qd * 4 + r) * 128 + nt * 16 + ln] = f2bf(v);
        }
    }

    if (isel) {
        __syncthreads();                                 // Tt complete
        int b2 = msel >> 5, q0 = (msel & 31) * 64;
        int dr = tid >> 3, j = tid & 7;
#pragma unroll
        for (int i = 0; i < 8; ++i) {
            int d = dr + i * 32;
            v8s vv = *(const v8s*)(Tt + d * 72 + j * 8);
            // chunk-XOR swizzle: granule j stored at position j^(d&7)
            *(v8s*)(VaT + ((size_t)(b2 * 256 + d)) * 2048 + q0 + ((j ^ (d & 7)) << 3)) = vv;
        }
        if (tid < 64) {
            int qq = b2 * 2048 + q0 + tid;
            maskadd[qq] = (qmask[qq] > 0) ? 0.f : -__builtin_inff();
        }
    }
}

// ------------- flash attention: IN-BLOCK kv-split, direct out -------------
// (verbatim R5 kernel: measured 54.5 us, passed.) 256 blocks x 512 thr
// (8 waves = 2 groups of 4). Group g owns kv-half [g*1024, +1024): 16 steps
// of 64 kv, depth-2 counted-vmcnt schedule per group (K/mask reg-prefetch
// 1 step ahead; V wave-private d-quarter dbuf via async global_load_lds;
// P per-group LDS chunk-XOR). End: group 1 dumps unnormalized O to LDS,
// group 0 merges, normalizes, writes out. NO partials in HBM, NO combine.
__global__ __launch_bounds__(512, 2) void k_attn(const short* __restrict__ Qa,
                                                 const short* __restrict__ Ka,
                                                 const short* __restrict__ VaT,
                                                 const float* __restrict__ maskadd,
                                                 float* __restrict__ out) {
    __shared__ __align__(16) short VaS[2][2][256 * 64];  // 128 KB [grp][buf]
    __shared__ __align__(16) short PS[2][64 * 64];       // 16 KB [grp] swizzled
    __shared__ float lS[8 * 64];                         // 2 KB

    const int STEPS = 16;
    int blk = blockIdx.x;
    int b = blk & 7;
    int c0 = (blk >> 3) * 64;

    int tid = threadIdx.x;
    int w = tid >> 6, lane = tid & 63, ln = lane & 15, qd = lane >> 4;
    int g = w >> 2, wl = w & 3;              // group, wave-in-group
    int kv0 = g * 1024;

    const short* qbase = Qa + (size_t)(b * 2048) * 128;
    const short* kbase = Ka + (size_t)(b * 2048 + kv0 + wl * 16 + ln) * 128 + qd * 8;
    const short* vbase = VaT + (size_t)(b * 256) * 2048;
    const float* mbase = maskadd + b * 2048 + kv0 + wl * 16 + qd * 4;

    // Q fragments for all 4 c-tiles (B-operand layout), resident
    v8s qf[4][4];
#pragma unroll
    for (int ct = 0; ct < 4; ++ct) {
        const short* qp = qbase + (size_t)(c0 + ct * 16 + ln) * 128 + qd * 8;
#pragma unroll
        for (int kk = 0; kk < 4; ++kk) qf[ct][kk] = *(const v8s*)(qp + kk * 32);
    }

    v4f zero = {0.f, 0.f, 0.f, 0.f};
    v4f o[4][4];                            // [ct][dt]
#pragma unroll
    for (int i = 0; i < 4; ++i)
#pragma unroll
        for (int j = 0; j < 4; ++j) o[i][j] = zero;
    float lacc[4] = {0.f, 0.f, 0.f, 0.f};

    // stage own d-quarter of V tile for kv window q0s into buf (wave-private)
    auto stageV = [&](int q0s, int buf) {
        short* base = &VaS[g][buf][0] + wl * 4096;   // rows wl*64..+63
#pragma unroll
        for (int j = 0; j < 8; ++j) {
            int U = (wl * 8 + j) * 64 + lane;        // 16B unit index
            int d = U >> 3, cc = U & 7;
            gload_lds16(vbase + (size_t)d * 2048 + q0s + cc * 8,
                        base + j * 512);
        }
    };

    // ---- prologue: stage0 | kf0 | stage1 (order pinned for in-order
    // vmcnt retirement arithmetic) ----
    v8s kfA[4], kfB[4];
    float4 mkA, mkB;
    stageV(kv0, 0);
    asm volatile("" ::: "memory");
#pragma unroll
    for (int kk = 0; kk < 4; ++kk) kfA[kk] = *(const v8s*)(kbase + kk * 32);
    mkA = *(const float4*)(mbase);
    asm volatile("" ::: "memory");
    stageV(kv0 + 64, 1);

#define ATT_STEP(IT, KFC, MKC, KFN, MKN) do {                                  \
    int q0 = kv0 + (IT) * 64;                                                  \
    int itn = ((IT) + 1) & (STEPS - 1);                                        \
    int itn2 = ((IT) + 2) & (STEPS - 1);                                       \
    {   /* prefetch NEXT step's K frags + mask into regs (5 VMEM) */           \
        const short* kp = kbase + (size_t)itn * 8192;                          \
        _Pragma("unroll")                                                      \
        for (int kk = 0; kk < 4; ++kk) KFN[kk] = *(const v8s*)(kp + kk * 32);  \
        MKN = *(const float4*)(mbase + itn * 64);                              \
    }                                                                          \
    /* retire stage(IT)+kf(IT); keep stage(IT+1)+kf(IT+1) = 13 in flight */    \
    asm volatile("s_waitcnt vmcnt(13)" ::: "memory");                          \
    int kvb = q0 + wl * 16 + qd * 4;                                           \
    _Pragma("unroll")                                                          \
    for (int ct = 0; ct < 4; ++ct) {                                           \
        v4f s = zero;                                                          \
        _Pragma("unroll")                                                      \
        for (int kk = 0; kk < 4; ++kk)                                         \
            s = __builtin_amdgcn_mfma_f32_16x16x32_bf16(KFC[kk], qf[ct][kk],   \
                                                        s, 0, 0, 0);           \
        int cg = c0 + ct * 16 + ln;                                            \
        v4s pw;                                                                \
        float ls = 0.f;                                                        \
        _Pragma("unroll")                                                      \
        for (int r = 0; r < 4; ++r) {                                          \
            float v = s[r] * SCL2 + (&MKC.x)[r];                               \
            if (kvb + r == cg) v = -__builtin_inff();                          \
            float p = exp2f(v);                                                \
            ls += p;                                                           \
            pw[r] = f2bf(p);                                                   \
        }                                                                      \
        lacc[ct] += ls;                                                        \
        int hs = ((wl * 2 + (qd >> 1)) ^ (ln & 7));                            \
        *(v4s*)(&PS[g][0] + (ct * 16 + ln) * 64 + hs * 8 + (qd & 1) * 4) = pw; \
    }                                                                          \
    asm volatile("s_waitcnt lgkmcnt(0)" ::: "memory");                         \
    __builtin_amdgcn_s_barrier();           /* P visible */                    \
    const short* vs = &VaS[g][(IT) & 1][0];                                    \
    __builtin_amdgcn_s_setprio(1);                                             \
    _Pragma("unroll")                                                          \
    for (int kk2 = 0; kk2 < 2; ++kk2) {                                        \
        v8s pf[4], vf[4];                                                      \
        _Pragma("unroll")                                                      \
        for (int ct = 0; ct < 4; ++ct)                                         \
            pf[ct] = *(const v8s*)(&PS[g][0] + (ct * 16 + ln) * 64 +           \
                                   (((kk2 * 4 + qd) ^ (ln & 7)) << 3));        \
        _Pragma("unroll")                                                      \
        for (int dt = 0; dt < 4; ++dt) {                                       \
            int d = wl * 64 + dt * 16 + ln;                                    \
            vf[dt] = *(const v8s*)(vs + d * 64 +                               \
                                   (((kk2 * 4 + qd) ^ (ln & 7)) << 3));        \
        }                                                                      \
        _Pragma("unroll")                                                      \
        for (int ct = 0; ct < 4; ++ct)                                         \
            _Pragma("unroll")                                                  \
            for (int dt = 0; dt < 4; ++dt)                                     \
                o[ct][dt] = __builtin_amdgcn_mfma_f32_16x16x32_bf16(           \
                    pf[ct], vf[dt], o[ct][dt], 0, 0, 0);                       \
    }                                                                          \
    __builtin_amdgcn_s_setprio(0);                                             \
    /* own P+V ds_reads drained -> safe to DMA-overwrite buf[(IT)&1] */        \
    asm volatile("s_waitcnt lgkmcnt(0)" ::: "memory");                         \
    stageV(kv0 + itn2 * 64, (IT) & 1);                                         \
    __builtin_amdgcn_s_barrier();           /* protect P for next write */     \
} while (0)

#pragma unroll 1
    for (int it2 = 0; it2 < STEPS; it2 += 2) {
        ATT_STEP(it2, kfA, mkA, kfB, mkB);
        ATT_STEP(it2 + 1, kfB, mkB, kfA, mkA);
    }
#undef ATT_STEP

    // ---- epilogue: drain trailing DMAs, then combine the two kv-halves ----
    asm volatile("s_waitcnt vmcnt(0)" ::: "memory");
    __syncthreads();

    // l: reduce over qd in-wave, publish per-wave sums
#pragma unroll
    for (int ct = 0; ct < 4; ++ct) {
        float v = lacc[ct];
        v += __shfl_xor(v, 16);
        v += __shfl_xor(v, 32);
        if (qd == 0) lS[w * 64 + ct * 16 + ln] = v;
    }

    // group 1 dumps unnormalized O into LDS (VaS reused; stride 260 pads
    // the 256-f32 row to kill the 4-way qd bank alias)
    float* OS = (float*)&VaS[0][0][0];       // [64 c][260 d-pad] f32, 66.6 KB
    if (g == 1) {
#pragma unroll
        for (int ct = 0; ct < 4; ++ct)
#pragma unroll
            for (int r = 0; r < 4; ++r)
#pragma unroll
                for (int dt = 0; dt < 4; ++dt)
                    OS[(ct * 16 + qd * 4 + r) * 260 + wl * 64 + dt * 16 + ln] =
                        o[ct][dt][r];
    }
    __syncthreads();

    if (g == 0) {
#pragma unroll
        for (int ct = 0; ct < 4; ++ct) {
            float lv[4];
#pragma unroll
            for (int r = 0; r < 4; ++r) {
                float s = 0.f;
#pragma unroll
                for (int wv = 0; wv < 8; ++wv)
                    s += lS[wv * 64 + ct * 16 + qd * 4 + r];
                lv[r] = s;
            }
            int rowg = b * 2048 + c0 + ct * 16 + qd * 4;
#pragma unroll
            for (int r = 0; r < 4; ++r) {
                float inv = 1.f / lv[r];
#pragma unroll
                for (int dt = 0; dt < 4; ++dt) {
                    int col = wl * 64 + dt * 16 + ln;
                    float sum = o[ct][dt][r] +
                                OS[(ct * 16 + qd * 4 + r) * 260 + col];
                    out[(size_t)(rowg + r) * 256 + col] = sum * inv;
                }
            }
        }
    }
}

extern "C" void kernel_launch(void* const* d_in, const int* in_sizes, int n_in,
                              void* d_out, int out_size, void* d_ws, size_t ws_size,
                              hipStream_t stream) {
    const float* ctx  = (const float*)d_in[0];
    const float* qry  = (const float*)d_in[1];
    const float* win  = (const float*)d_in[2];
    const float* wmem = (const float*)d_in[3];
    const int* qmask  = (const int*)d_in[4];
    float* out = (float*)d_out;

    char* ws = (char*)d_ws;
    short* Qa      = (short*)(ws);                          // 4 MB
    short* Ka      = (short*)(ws + (4u << 20));             // 4 MB
    short* VaT     = (short*)(ws + (8u << 20));             // 8 MB (chunk-XOR swizzled)
    float* maskadd = (float*)(ws + (16u << 20));            // 64 KB

    k_pre<<<dim3(512), 256, 0, stream>>>(ctx, qry, win, wmem, qmask,
                                         Qa, Ka, VaT, maskadd);
    k_attn<<<dim3(256), 512, 0, stream>>>(Qa, Ka, VaT, maskadd, out);
}